// Round 1
// baseline (341.377 us; speedup 1.0000x reference)
//
#include <hip/hip_runtime.h>
#include <cstdint>
#include <cstddef>
#include <math.h>

#define NN 100000
#define NE 1600000
#define NB ((NN + 255) / 256)   // 391 node buckets (256 nodes each)
#define EB 400                  // build blocks
#define EPB (NE / EB)           // 4000 edges per block
#define CAP 5120                // padded bucket capacity (mean 4092, sigma~64)

// GEMM tiling: 512 threads, 128 nodes/block, per-thread 4 nodes x 4 feats.
#define GT_NODES 128
#define GT_KC 32
#define GT_STRIDE 132

typedef unsigned short u16;

__device__ __forceinline__ float bf2f(u16 u) {
    union { unsigned i; float f; } c; c.i = ((unsigned)u) << 16; return c.f;
}
__device__ __forceinline__ u16 f2bf(float f) {  // round-to-nearest-even
    union { float f; unsigned int i; } c; c.f = f;
    unsigned int lsb = (c.i >> 16) & 1u;
    return (u16)((c.i + 0x7fffu + lsb) >> 16);
}
__device__ __forceinline__ unsigned int pack2(float a, float b) {
    return (unsigned int)f2bf(a) | ((unsigned int)f2bf(b) << 16);
}

__device__ __forceinline__ int load_idx(const void* ei, int isI64, int pos) {
    if (isI64) return (int)((const long long*)ei)[pos];
    return ((const int*)ei)[pos];
}

// ---------- fused CSR phase A: detect + hist + scatter into padded buckets ----
// One block = 4000 edges staged in LDS; per-bucket LDS counts; ONE global
// atomicAdd per (block,bucket) reserves a run in csr_tmp[j*CAP ..]; then LDS
// entries are scattered out. Replaces k_detect/k_hist/k_colscan/k_bucketscan/
// k_scatter of the 6-kernel build.
__global__ __launch_bounds__(256) void k_build(const void* __restrict__ ei,
                                               int* __restrict__ cursor,
                                               int* __restrict__ csr_tmp) {
    __shared__ int sbuf[EPB];      // 16,000 B
    __shared__ int dbuf[EPB];      // 16,000 B
    __shared__ int cnt[NB];
    __shared__ int basel[NB];
    __shared__ int anynz;

    // per-block int64/int32 detection (odd words of first 1024 entries)
    const int* p = (const int*)ei;
    if (threadIdx.x == 0) anynz = 0;
    for (int i = threadIdx.x; i < NB; i += 256) cnt[i] = 0;
    __syncthreads();
    int nz = 0;
    for (int i = threadIdx.x; i < 1024; i += 256) nz |= (p[2 * i + 1] != 0);
    if (nz) anynz = 1;   // benign race: all writers store 1
    __syncthreads();
    int isI64 = (anynz == 0);

    int base = blockIdx.x * EPB;
    for (int i = threadIdx.x; i < EPB; i += 256) {
        int s = load_idx(ei, isI64, base + i);
        int d = load_idx(ei, isI64, NE + base + i);
        sbuf[i] = s;
        dbuf[i] = d;
        atomicAdd(&cnt[d >> 8], 1);
    }
    __syncthreads();
    for (int j = threadIdx.x; j < NB; j += 256) {
        int c = cnt[j];
        int g = c ? atomicAdd(&cursor[j], c) : 0;
        basel[j] = j * CAP + g;
        cnt[j] = 0;   // reuse as local placement cursor
    }
    __syncthreads();
    for (int i = threadIdx.x; i < EPB; i += 256) {
        int s = sbuf[i];
        int d = dbuf[i];
        int bkt = d >> 8;
        int slot = basel[bkt] + atomicAdd(&cnt[bkt], 1);
        csr_tmp[slot] = ((d & 255) << 17) | s;   // dstlocal<<17 | src
    }
}

// ---------- CSR phase B: per-bucket counting sort -> csr + deg/offs/dis ------
// Bucket j's entries live in csr_tmp[j*CAP .. j*CAP+cursor[j]); final csr uses
// the same padded layout, so offs[node] = j*CAP + local_exclusive_prefix.
__global__ __launch_bounds__(256) void k_sort(const int* __restrict__ cursor,
                                              const int* __restrict__ csr_tmp,
                                              int* __restrict__ csr,
                                              int* __restrict__ deg,
                                              int* __restrict__ offs,
                                              float* __restrict__ dis) {
    __shared__ int h[256];
    __shared__ int sc[256];
    __shared__ int cur[256];
    int j = blockIdx.x;
    int s0 = j * CAP, s1 = s0 + cursor[j];
    h[threadIdx.x] = 0;
    __syncthreads();
    for (int p = s0 + threadIdx.x; p < s1; p += 256)
        atomicAdd(&h[csr_tmp[p] >> 17], 1);
    __syncthreads();
    int v = h[threadIdx.x];
    sc[threadIdx.x] = v;
    __syncthreads();
#pragma unroll
    for (int off = 1; off < 256; off <<= 1) {
        int u = (threadIdx.x >= off) ? sc[threadIdx.x - off] : 0;
        __syncthreads();
        sc[threadIdx.x] += u;
        __syncthreads();
    }
    int excl = sc[threadIdx.x] - v;
    int node = j * 256 + threadIdx.x;
    if (node < NN) {
        deg[node] = v;
        offs[node] = s0 + excl;
        dis[node] = rsqrtf((float)(v + 1));  // +1 self-loop
    }
    cur[threadIdx.x] = excl;
    __syncthreads();
    for (int p = s0 + threadIdx.x; p < s1; p += 256) {
        int pk = csr_tmp[p];
        int dl = pk >> 17;
        int pos = s0 + atomicAdd(&cur[dl], 1);
        csr[pos] = pk & 0x1FFFF;   // plain src index
    }
}

// ---------- register-tiled GEMM (512 thr, 128 nodes/blk, 4x4/thread) ----------
// g[n][j] = bf16( dis[n] * (act(x)[n][:] @ W[:][j]) )
template <int K, int FR, bool RELU>
__global__ __launch_bounds__(512) void k_gemm(const float* __restrict__ x,
                                              const float* __restrict__ W,
                                              const float* __restrict__ dis,
                                              u16* __restrict__ out) {
    __shared__ float xT[GT_KC * GT_STRIDE];   // 16,896 B
    __shared__ float Wc[GT_KC * 64];          //  8,192 B
    const int tid = threadIdx.x;
    const int r = tid >> 4;
    const int c = tid & 15;
    const int f4 = tid & 7;
    const int nrow = tid >> 3;
    const int nbase = blockIdx.x * GT_NODES;

    float acc[4][4];
#pragma unroll
    for (int i = 0; i < 4; ++i)
#pragma unroll
        for (int j = 0; j < 4; ++j) acc[i][j] = 0.f;

    for (int kc = 0; kc < K; kc += GT_KC) {
#pragma unroll
        for (int q = 0; q < 4; ++q) {
            int e = q * 512 + tid;
            int kk = e >> 6, j = e & 63;
            Wc[kk * 64 + j] = (j < FR) ? W[(size_t)(kc + kk) * FR + j] : 0.f;
        }
#pragma unroll
        for (int q = 0; q < 2; ++q) {
            int nl = q * 64 + nrow;
            int n = nbase + nl;
            float4 v = make_float4(0.f, 0.f, 0.f, 0.f);
            if (n < NN) v = *(const float4*)(x + (size_t)n * K + kc + f4 * 4);
            if (RELU) {
                v.x = fmaxf(v.x, 0.f); v.y = fmaxf(v.y, 0.f);
                v.z = fmaxf(v.z, 0.f); v.w = fmaxf(v.w, 0.f);
            }
            xT[(f4 * 4 + 0) * GT_STRIDE + nl] = v.x;
            xT[(f4 * 4 + 1) * GT_STRIDE + nl] = v.y;
            xT[(f4 * 4 + 2) * GT_STRIDE + nl] = v.z;
            xT[(f4 * 4 + 3) * GT_STRIDE + nl] = v.w;
        }
        __syncthreads();
#pragma unroll 8
        for (int kk = 0; kk < GT_KC; ++kk) {
            float4 a = *(const float4*)&xT[kk * GT_STRIDE + r * 4];
            float4 w = *(const float4*)&Wc[kk * 64 + c * 4];
            float xa[4] = {a.x, a.y, a.z, a.w};
            float wb[4] = {w.x, w.y, w.z, w.w};
#pragma unroll
            for (int i = 0; i < 4; ++i)
#pragma unroll
                for (int j = 0; j < 4; ++j)
                    acc[i][j] = fmaf(xa[i], wb[j], acc[i][j]);
        }
        __syncthreads();
    }
    if (c * 4 < FR) {
#pragma unroll
        for (int i = 0; i < 4; ++i) {
            int n = nbase + r * 4 + i;
            if (n < NN) {
                float dv = dis[n];
                uint2 o;
                o.x = pack2(dv * acc[i][0], dv * acc[i][1]);
                o.y = pack2(dv * acc[i][2], dv * acc[i][3]);
                *(uint2*)(out + (size_t)n * FR + c * 4) = o;
            }
        }
    }
}

// ---------- gather aggregation (round-6 measured-optimal form) ----------
// out[n][f] = dis[n] * ( g[n][f] + sum_e g[src_e][f] ) + b[f]
// Per edge: broadcast dword csr load + readfirstlane -> row base on the
// scalar pipe; 8 independent gathers in flight. DO NOT restructure: int4
// batching (R10), quad-rows (R9), s_load (R8) all measured slower.
template <int F, bool SOFTMAX>
__global__ __launch_bounds__(256) void k_gather(const int* __restrict__ offs,
                                                const int* __restrict__ deg,
                                                const int* __restrict__ csr,
                                                const float* __restrict__ dis,
                                                const u16* __restrict__ g,
                                                const float* __restrict__ b,
                                                float* __restrict__ out) {
    int n = blockIdx.x * 4 + (threadIdx.x >> 6);
    unsigned f = threadIdx.x & 63;
    if (n >= NN) return;
    unsigned fc = (f < (unsigned)F) ? f : 0u;
    int start = __builtin_amdgcn_readfirstlane(offs[n]);
    int len   = __builtin_amdgcn_readfirstlane(deg[n]);
    float dvn = dis[n];
    float bf  = b[fc];
    float acc = bf2f(g[(unsigned)n * F + fc]);  // self-loop (pre-scaled)
    int i = 0;
    for (; i + 8 <= len; i += 8) {
        int s0 = __builtin_amdgcn_readfirstlane(csr[start + i + 0]);
        int s1 = __builtin_amdgcn_readfirstlane(csr[start + i + 1]);
        int s2 = __builtin_amdgcn_readfirstlane(csr[start + i + 2]);
        int s3 = __builtin_amdgcn_readfirstlane(csr[start + i + 3]);
        int s4 = __builtin_amdgcn_readfirstlane(csr[start + i + 4]);
        int s5 = __builtin_amdgcn_readfirstlane(csr[start + i + 5]);
        int s6 = __builtin_amdgcn_readfirstlane(csr[start + i + 6]);
        int s7 = __builtin_amdgcn_readfirstlane(csr[start + i + 7]);
        u16 h0 = g[(unsigned)s0 * F + fc];
        u16 h1 = g[(unsigned)s1 * F + fc];
        u16 h2 = g[(unsigned)s2 * F + fc];
        u16 h3 = g[(unsigned)s3 * F + fc];
        u16 h4 = g[(unsigned)s4 * F + fc];
        u16 h5 = g[(unsigned)s5 * F + fc];
        u16 h6 = g[(unsigned)s6 * F + fc];
        u16 h7 = g[(unsigned)s7 * F + fc];
        acc += bf2f(h0) + bf2f(h1) + bf2f(h2) + bf2f(h3)
             + bf2f(h4) + bf2f(h5) + bf2f(h6) + bf2f(h7);
    }
    for (; i + 2 <= len; i += 2) {
        int s0 = __builtin_amdgcn_readfirstlane(csr[start + i + 0]);
        int s1 = __builtin_amdgcn_readfirstlane(csr[start + i + 1]);
        u16 h0 = g[(unsigned)s0 * F + fc];
        u16 h1 = g[(unsigned)s1 * F + fc];
        acc += bf2f(h0) + bf2f(h1);
    }
    if (i < len) {
        int s0 = __builtin_amdgcn_readfirstlane(csr[start + i]);
        acc += bf2f(g[(unsigned)s0 * F + fc]);
    }
    float v = dvn * acc + bf;
    if (!SOFTMAX) {
        if (f < (unsigned)F) out[(size_t)n * F + f] = v;
    } else {
        float vv = (f < (unsigned)F) ? v : -INFINITY;
        float m = vv;
#pragma unroll
        for (int off = 32; off; off >>= 1) m = fmaxf(m, __shfl_xor(m, off));
        float ex = (f < (unsigned)F) ? __expf(vv - m) : 0.f;
        float sum = ex;
#pragma unroll
        for (int off = 32; off; off >>= 1) sum += __shfl_xor(sum, off);
        if (f < (unsigned)F) out[(size_t)n * F + f] = vv - m - logf(sum);
    }
}

extern "C" void kernel_launch(void* const* d_in, const int* in_sizes, int n_in,
                              void* d_out, int out_size, void* d_ws, size_t ws_size,
                              hipStream_t stream) {
    const float* x  = (const float*)d_in[0];
    const void*  ei = d_in[1];
    const float* W1 = (const float*)d_in[2];
    const float* b1 = (const float*)d_in[3];
    const float* W2 = (const float*)d_in[4];
    const float* b2 = (const float*)d_in[5];
    const float* W3 = (const float*)d_in[6];
    const float* b3 = (const float*)d_in[7];
    float* out = (float*)d_out;

    char* ws = (char*)d_ws;
    size_t off = 0;
    auto alloc = [&](size_t bytes) { void* p = ws + off; off += (bytes + 255) & ~255ULL; return p; };
    int*   cursor  = (int*)alloc(NB * 4);
    int*   deg     = (int*)alloc(NN * 4);
    float* dis     = (float*)alloc(NN * 4);
    int*   offs    = (int*)alloc(NN * 4);
    int*   csr_tmp = (int*)alloc((size_t)NB * CAP * 4);   // 8 MB padded
    int*   csr     = (int*)alloc((size_t)NB * CAP * 4);   // 8 MB padded
    u16*   gbuf    = (u16*)alloc((size_t)NN * 64 * 2);    // bf16 staging (12.8 MB)
    float* act     = (float*)alloc((size_t)NN * 64 * 4);  // fp32 inter-layer activations

    // CSR build: 2 kernels (padded-bucket counting sort, no global prefix)
    hipMemsetAsync(cursor, 0, NB * 4, stream);
    k_build<<<EB, 256, 0, stream>>>(ei, cursor, csr_tmp);
    k_sort<<<NB, 256, 0, stream>>>(cursor, csr_tmp, csr, deg, offs, dis);

    const int gemm_grid = (NN + GT_NODES - 1) / GT_NODES;   // 782
    const int gather_grid = (NN + 3) / 4;

    // layer 1: g1 = bf16(dis*(x@W1)); out1 = dis*(sum g1) + b1  (ReLU fused into next gemm)
    k_gemm<128, 64, false><<<gemm_grid, 512, 0, stream>>>(x, W1, dis, gbuf);
    k_gather<64, false><<<gather_grid, 256, 0, stream>>>(offs, deg, csr, dis, gbuf, b1, act);

    // layer 2
    k_gemm<64, 64, true><<<gemm_grid, 512, 0, stream>>>(act, W2, dis, gbuf);
    k_gather<64, false><<<gather_grid, 256, 0, stream>>>(offs, deg, csr, dis, gbuf, b2, act);

    // layer 3 + fused log_softmax (tight 40-wide staging rows)
    k_gemm<64, 40, true><<<gemm_grid, 512, 0, stream>>>(act, W3, dis, gbuf);
    k_gather<40, true><<<gather_grid, 256, 0, stream>>>(offs, deg, csr, dis, gbuf, b3, out);
}

// Round 2
// 338.543 us; speedup vs baseline: 1.0084x; 1.0084x over previous
//
#include <hip/hip_runtime.h>
#include <cstdint>
#include <cstddef>
#include <math.h>

#define NN 100000
#define NE 1600000
#define NB ((NN + 255) / 256)   // 391 node buckets (256 nodes each)
#define EB 400                  // build blocks
#define EPB (NE / EB)           // 4000 edges per block
#define CAP 5120                // padded bucket capacity (mean 4092, sigma~64)

// GEMM tiling: 512 threads, 128 nodes/block, per-thread 4 nodes x 4 feats.
#define GT_NODES 128
#define GT_KC 32
#define GT_STRIDE 132

typedef unsigned short u16;

__device__ __forceinline__ float bf2f(u16 u) {
    union { unsigned i; float f; } c; c.i = ((unsigned)u) << 16; return c.f;
}
__device__ __forceinline__ u16 f2bf(float f) {  // round-to-nearest-even
    union { float f; unsigned int i; } c; c.f = f;
    unsigned int lsb = (c.i >> 16) & 1u;
    return (u16)((c.i + 0x7fffu + lsb) >> 16);
}
__device__ __forceinline__ unsigned int pack2(float a, float b) {
    return (unsigned int)f2bf(a) | ((unsigned int)f2bf(b) << 16);
}

__device__ __forceinline__ int load_idx(const void* ei, int isI64, int pos) {
    if (isI64) return (int)((const long long*)ei)[pos];
    return ((const int*)ei)[pos];
}

// ---------- fused CSR phase A: detect + hist + scatter into padded buckets ----
__global__ __launch_bounds__(256) void k_build(const void* __restrict__ ei,
                                               int* __restrict__ cursor,
                                               int* __restrict__ csr_tmp) {
    __shared__ int sbuf[EPB];      // 16,000 B
    __shared__ int dbuf[EPB];      // 16,000 B
    __shared__ int cnt[NB];
    __shared__ int basel[NB];
    __shared__ int anynz;

    // per-block int64/int32 detection (odd words of first 1024 entries)
    const int* p = (const int*)ei;
    if (threadIdx.x == 0) anynz = 0;
    for (int i = threadIdx.x; i < NB; i += 256) cnt[i] = 0;
    __syncthreads();
    int nz = 0;
    for (int i = threadIdx.x; i < 1024; i += 256) nz |= (p[2 * i + 1] != 0);
    if (nz) anynz = 1;   // benign race: all writers store 1
    __syncthreads();
    int isI64 = (anynz == 0);

    int base = blockIdx.x * EPB;
    for (int i = threadIdx.x; i < EPB; i += 256) {
        int s = load_idx(ei, isI64, base + i);
        int d = load_idx(ei, isI64, NE + base + i);
        sbuf[i] = s;
        dbuf[i] = d;
        atomicAdd(&cnt[d >> 8], 1);
    }
    __syncthreads();
    for (int j = threadIdx.x; j < NB; j += 256) {
        int c = cnt[j];
        int g = c ? atomicAdd(&cursor[j], c) : 0;
        basel[j] = j * CAP + g;
        cnt[j] = 0;   // reuse as local placement cursor
    }
    __syncthreads();
    for (int i = threadIdx.x; i < EPB; i += 256) {
        int s = sbuf[i];
        int d = dbuf[i];
        int bkt = d >> 8;
        int slot = basel[bkt] + atomicAdd(&cnt[bkt], 1);
        csr_tmp[slot] = ((d & 255) << 17) | s;   // dstlocal<<17 | src
    }
}

// ---------- CSR phase B: per-bucket counting sort -> csr + deg/offs/dis ------
__global__ __launch_bounds__(256) void k_sort(const int* __restrict__ cursor,
                                              const int* __restrict__ csr_tmp,
                                              int* __restrict__ csr,
                                              int* __restrict__ deg,
                                              int* __restrict__ offs,
                                              float* __restrict__ dis) {
    __shared__ int h[256];
    __shared__ int sc[256];
    __shared__ int cur[256];
    int j = blockIdx.x;
    int s0 = j * CAP, s1 = s0 + cursor[j];
    h[threadIdx.x] = 0;
    __syncthreads();
    for (int p = s0 + threadIdx.x; p < s1; p += 256)
        atomicAdd(&h[csr_tmp[p] >> 17], 1);
    __syncthreads();
    int v = h[threadIdx.x];
    sc[threadIdx.x] = v;
    __syncthreads();
#pragma unroll
    for (int off = 1; off < 256; off <<= 1) {
        int u = (threadIdx.x >= off) ? sc[threadIdx.x - off] : 0;
        __syncthreads();
        sc[threadIdx.x] += u;
        __syncthreads();
    }
    int excl = sc[threadIdx.x] - v;
    int node = j * 256 + threadIdx.x;
    if (node < NN) {
        deg[node] = v;
        offs[node] = s0 + excl;
        dis[node] = rsqrtf((float)(v + 1));  // +1 self-loop
    }
    cur[threadIdx.x] = excl;
    __syncthreads();
    for (int p = s0 + threadIdx.x; p < s1; p += 256) {
        int pk = csr_tmp[p];
        int dl = pk >> 17;
        int pos = s0 + atomicAdd(&cur[dl], 1);
        csr[pos] = pk & 0x1FFFF;   // plain src index
    }
}

// ---------- register-tiled GEMM (512 thr, 128 nodes/blk, 4x4/thread) ----------
template <int K, int FR, bool RELU>
__global__ __launch_bounds__(512) void k_gemm(const float* __restrict__ x,
                                              const float* __restrict__ W,
                                              const float* __restrict__ dis,
                                              u16* __restrict__ out) {
    __shared__ float xT[GT_KC * GT_STRIDE];   // 16,896 B
    __shared__ float Wc[GT_KC * 64];          //  8,192 B
    const int tid = threadIdx.x;
    const int r = tid >> 4;
    const int c = tid & 15;
    const int f4 = tid & 7;
    const int nrow = tid >> 3;
    const int nbase = blockIdx.x * GT_NODES;

    float acc[4][4];
#pragma unroll
    for (int i = 0; i < 4; ++i)
#pragma unroll
        for (int j = 0; j < 4; ++j) acc[i][j] = 0.f;

    for (int kc = 0; kc < K; kc += GT_KC) {
#pragma unroll
        for (int q = 0; q < 4; ++q) {
            int e = q * 512 + tid;
            int kk = e >> 6, j = e & 63;
            Wc[kk * 64 + j] = (j < FR) ? W[(size_t)(kc + kk) * FR + j] : 0.f;
        }
#pragma unroll
        for (int q = 0; q < 2; ++q) {
            int nl = q * 64 + nrow;
            int n = nbase + nl;
            float4 v = make_float4(0.f, 0.f, 0.f, 0.f);
            if (n < NN) v = *(const float4*)(x + (size_t)n * K + kc + f4 * 4);
            if (RELU) {
                v.x = fmaxf(v.x, 0.f); v.y = fmaxf(v.y, 0.f);
                v.z = fmaxf(v.z, 0.f); v.w = fmaxf(v.w, 0.f);
            }
            xT[(f4 * 4 + 0) * GT_STRIDE + nl] = v.x;
            xT[(f4 * 4 + 1) * GT_STRIDE + nl] = v.y;
            xT[(f4 * 4 + 2) * GT_STRIDE + nl] = v.z;
            xT[(f4 * 4 + 3) * GT_STRIDE + nl] = v.w;
        }
        __syncthreads();
#pragma unroll 8
        for (int kk = 0; kk < GT_KC; ++kk) {
            float4 a = *(const float4*)&xT[kk * GT_STRIDE + r * 4];
            float4 w = *(const float4*)&Wc[kk * 64 + c * 4];
            float xa[4] = {a.x, a.y, a.z, a.w};
            float wb[4] = {w.x, w.y, w.z, w.w};
#pragma unroll
            for (int i = 0; i < 4; ++i)
#pragma unroll
                for (int j = 0; j < 4; ++j)
                    acc[i][j] = fmaf(xa[i], wb[j], acc[i][j]);
        }
        __syncthreads();
    }
    if (c * 4 < FR) {
#pragma unroll
        for (int i = 0; i < 4; ++i) {
            int n = nbase + r * 4 + i;
            if (n < NN) {
                float dv = dis[n];
                uint2 o;
                o.x = pack2(dv * acc[i][0], dv * acc[i][1]);
                o.y = pack2(dv * acc[i][2], dv * acc[i][3]);
                *(uint2*)(out + (size_t)n * FR + c * 4) = o;
            }
        }
    }
}

// ---------- gather batch helper: B edges, indices pre-staged in myidx --------
// Indices delivered via v_readlane (register op, no memory latency); gather
// addresses form as SALU base + invariant voffset. Out-of-range slots hit
// row 0 (staged idx 0) and are cndmask'ed to zero.
template <int B, int F>
__device__ __forceinline__ float gbatch(int myidx, int i, int lim,
                                        const u16* __restrict__ g, unsigned fc) {
    int ss[B];
    u16 hh[B];
#pragma unroll
    for (int k = 0; k < B; ++k) ss[k] = __builtin_amdgcn_readlane(myidx, i + k);
#pragma unroll
    for (int k = 0; k < B; ++k) hh[k] = g[(unsigned)ss[k] * F + fc];
    float t0 = 0.f, t1 = 0.f, t2 = 0.f, t3 = 0.f;
#pragma unroll
    for (int k = 0; k < B; ++k) {
        float v = bf2f(hh[k]);
        v = (i + k < lim) ? v : 0.f;
        if ((k & 3) == 0) t0 += v;
        else if ((k & 3) == 1) t1 += v;
        else if ((k & 3) == 2) t2 += v;
        else t3 += v;
    }
    return (t0 + t1) + (t2 + t3);
}

// ---------- gather aggregation (R12: staged-index batched form) ----------
// out[n][f] = dis[n] * ( g[n][f] + sum_e g[src_e][f] ) + b[f]
// R12: stage up to 64 csr indices across the wave's lanes with ONE vector
// load, extract per-edge via v_readlane -> the per-batch csr-load->gather
// serial chain collapses to {1 staged load wait + 1 gather wait} for
// deg<=32 (99.98% of nodes at Poisson(16)). Addressing form preserved from
// the round-6 measured optimum (SGPR row base + invariant voffset).
// Historical: int4 batching (R10), quad-rows (R9), s_load (R8) all slower.
template <int F, bool SOFTMAX>
__global__ __launch_bounds__(256) void k_gather(const int* __restrict__ offs,
                                                const int* __restrict__ deg,
                                                const int* __restrict__ csr,
                                                const float* __restrict__ dis,
                                                const u16* __restrict__ g,
                                                const float* __restrict__ b,
                                                float* __restrict__ out) {
    int n = blockIdx.x * 4 + (threadIdx.x >> 6);
    unsigned f = threadIdx.x & 63;
    if (n >= NN) return;
    unsigned fc = (f < (unsigned)F) ? f : 0u;
    int start = __builtin_amdgcn_readfirstlane(offs[n]);
    int len   = __builtin_amdgcn_readfirstlane(deg[n]);
    float dvn = dis[n];
    float bf  = b[fc];
    float acc = bf2f(g[(unsigned)n * F + fc]);  // self-loop (pre-scaled)

    // stage up to 64 csr indices across lanes (one vector load, masked)
    int myidx = 0;
    if ((int)f < len) myidx = csr[start + (int)f];
    int lim = (len < 64) ? len : 64;

    if (lim > 0) {
        if (lim <= 16) {
            acc += gbatch<16, F>(myidx, 0, lim, g, fc);
        } else {
            acc += gbatch<32, F>(myidx, 0, lim, g, fc);
            for (int i = 32; i < lim; i += 16)
                acc += gbatch<16, F>(myidx, i, lim, g, fc);
        }
    }

    // rare fallback: deg > 64 (essentially never for Poisson(16))
    if (len > 64) {
        int ii = 64;
        for (; ii + 2 <= len; ii += 2) {
            int s0 = __builtin_amdgcn_readfirstlane(csr[start + ii + 0]);
            int s1 = __builtin_amdgcn_readfirstlane(csr[start + ii + 1]);
            u16 h0 = g[(unsigned)s0 * F + fc];
            u16 h1 = g[(unsigned)s1 * F + fc];
            acc += bf2f(h0) + bf2f(h1);
        }
        if (ii < len) {
            int s0 = __builtin_amdgcn_readfirstlane(csr[start + ii]);
            acc += bf2f(g[(unsigned)s0 * F + fc]);
        }
    }

    float v = dvn * acc + bf;
    if (!SOFTMAX) {
        if (f < (unsigned)F) out[(size_t)n * F + f] = v;
    } else {
        float vv = (f < (unsigned)F) ? v : -INFINITY;
        float m = vv;
#pragma unroll
        for (int off = 32; off; off >>= 1) m = fmaxf(m, __shfl_xor(m, off));
        float ex = (f < (unsigned)F) ? __expf(vv - m) : 0.f;
        float sum = ex;
#pragma unroll
        for (int off = 32; off; off >>= 1) sum += __shfl_xor(sum, off);
        if (f < (unsigned)F) out[(size_t)n * F + f] = vv - m - logf(sum);
    }
}

extern "C" void kernel_launch(void* const* d_in, const int* in_sizes, int n_in,
                              void* d_out, int out_size, void* d_ws, size_t ws_size,
                              hipStream_t stream) {
    const float* x  = (const float*)d_in[0];
    const void*  ei = d_in[1];
    const float* W1 = (const float*)d_in[2];
    const float* b1 = (const float*)d_in[3];
    const float* W2 = (const float*)d_in[4];
    const float* b2 = (const float*)d_in[5];
    const float* W3 = (const float*)d_in[6];
    const float* b3 = (const float*)d_in[7];
    float* out = (float*)d_out;

    char* ws = (char*)d_ws;
    size_t off = 0;
    auto alloc = [&](size_t bytes) { void* p = ws + off; off += (bytes + 255) & ~255ULL; return p; };
    int*   cursor  = (int*)alloc(NB * 4);
    int*   deg     = (int*)alloc(NN * 4);
    float* dis     = (float*)alloc(NN * 4);
    int*   offs    = (int*)alloc(NN * 4);
    int*   csr_tmp = (int*)alloc((size_t)NB * CAP * 4);   // 8 MB padded
    int*   csr     = (int*)alloc((size_t)NB * CAP * 4);   // 8 MB padded
    u16*   gbuf    = (u16*)alloc((size_t)NN * 64 * 2);    // bf16 staging (12.8 MB)
    float* act     = (float*)alloc((size_t)NN * 64 * 4);  // fp32 inter-layer activations

    // CSR build: 2 kernels (padded-bucket counting sort, no global prefix)
    hipMemsetAsync(cursor, 0, NB * 4, stream);
    k_build<<<EB, 256, 0, stream>>>(ei, cursor, csr_tmp);
    k_sort<<<NB, 256, 0, stream>>>(cursor, csr_tmp, csr, deg, offs, dis);

    const int gemm_grid = (NN + GT_NODES - 1) / GT_NODES;   // 782
    const int gather_grid = (NN + 3) / 4;

    // layer 1: g1 = bf16(dis*(x@W1)); out1 = dis*(sum g1) + b1  (ReLU fused into next gemm)
    k_gemm<128, 64, false><<<gemm_grid, 512, 0, stream>>>(x, W1, dis, gbuf);
    k_gather<64, false><<<gather_grid, 256, 0, stream>>>(offs, deg, csr, dis, gbuf, b1, act);

    // layer 2
    k_gemm<64, 64, true><<<gemm_grid, 512, 0, stream>>>(act, W2, dis, gbuf);
    k_gather<64, false><<<gather_grid, 256, 0, stream>>>(offs, deg, csr, dis, gbuf, b2, act);

    // layer 3 + fused log_softmax (tight 40-wide staging rows)
    k_gemm<64, 40, true><<<gemm_grid, 512, 0, stream>>>(act, W3, dis, gbuf);
    k_gather<40, true><<<gather_grid, 256, 0, stream>>>(offs, deg, csr, dis, gbuf, b3, out);
}

// Round 3
// 323.007 us; speedup vs baseline: 1.0569x; 1.0481x over previous
//
#include <hip/hip_runtime.h>
#include <cstdint>
#include <cstddef>
#include <math.h>

#define NN 100000
#define NE 1600000
#define NB ((NN + 255) / 256)   // 391 node buckets (256 nodes each)
#define EB 400                  // build blocks
#define EPB (NE / EB)           // 4000 edges per block
#define CAP 5120                // padded bucket capacity (mean 4092, sigma~64)

// GEMM tiling: 512 threads, 128 nodes/block, per-thread 4 nodes x 4 feats.
#define GT_NODES 128
#define GT_KC 32
#define GT_STRIDE 132

typedef unsigned short u16;

__device__ __forceinline__ float bf2f(u16 u) {
    union { unsigned i; float f; } c; c.i = ((unsigned)u) << 16; return c.f;
}
__device__ __forceinline__ u16 f2bf(float f) {  // round-to-nearest-even
    union { float f; unsigned int i; } c; c.f = f;
    unsigned int lsb = (c.i >> 16) & 1u;
    return (u16)((c.i + 0x7fffu + lsb) >> 16);
}
__device__ __forceinline__ unsigned int pack2(float a, float b) {
    return (unsigned int)f2bf(a) | ((unsigned int)f2bf(b) << 16);
}

__device__ __forceinline__ int load_idx(const void* ei, int isI64, int pos) {
    if (isI64) return (int)((const long long*)ei)[pos];
    return ((const int*)ei)[pos];
}

// ---------- fused CSR phase A: detect + hist + scatter into padded buckets ----
__global__ __launch_bounds__(256) void k_build(const void* __restrict__ ei,
                                               int* __restrict__ cursor,
                                               int* __restrict__ csr_tmp) {
    __shared__ int sbuf[EPB];      // 16,000 B
    __shared__ int dbuf[EPB];      // 16,000 B
    __shared__ int cnt[NB];
    __shared__ int basel[NB];
    __shared__ int anynz;

    // per-block int64/int32 detection (odd words of first 1024 entries)
    const int* p = (const int*)ei;
    if (threadIdx.x == 0) anynz = 0;
    for (int i = threadIdx.x; i < NB; i += 256) cnt[i] = 0;
    __syncthreads();
    int nz = 0;
    for (int i = threadIdx.x; i < 1024; i += 256) nz |= (p[2 * i + 1] != 0);
    if (nz) anynz = 1;   // benign race: all writers store 1
    __syncthreads();
    int isI64 = (anynz == 0);

    int base = blockIdx.x * EPB;
    for (int i = threadIdx.x; i < EPB; i += 256) {
        int s = load_idx(ei, isI64, base + i);
        int d = load_idx(ei, isI64, NE + base + i);
        sbuf[i] = s;
        dbuf[i] = d;
        atomicAdd(&cnt[d >> 8], 1);
    }
    __syncthreads();
    for (int j = threadIdx.x; j < NB; j += 256) {
        int c = cnt[j];
        int g = c ? atomicAdd(&cursor[j], c) : 0;
        basel[j] = j * CAP + g;
        cnt[j] = 0;   // reuse as local placement cursor
    }
    __syncthreads();
    for (int i = threadIdx.x; i < EPB; i += 256) {
        int s = sbuf[i];
        int d = dbuf[i];
        int bkt = d >> 8;
        int slot = basel[bkt] + atomicAdd(&cnt[bkt], 1);
        csr_tmp[slot] = ((d & 255) << 17) | s;   // dstlocal<<17 | src
    }
}

// ---------- CSR phase B: per-bucket counting sort -> csr + deg/offs/dis ------
__global__ __launch_bounds__(256) void k_sort(const int* __restrict__ cursor,
                                              const int* __restrict__ csr_tmp,
                                              int* __restrict__ csr,
                                              int* __restrict__ deg,
                                              int* __restrict__ offs,
                                              float* __restrict__ dis) {
    __shared__ int h[256];
    __shared__ int sc[256];
    __shared__ int cur[256];
    int j = blockIdx.x;
    int s0 = j * CAP, s1 = s0 + cursor[j];
    h[threadIdx.x] = 0;
    __syncthreads();
    for (int p = s0 + threadIdx.x; p < s1; p += 256)
        atomicAdd(&h[csr_tmp[p] >> 17], 1);
    __syncthreads();
    int v = h[threadIdx.x];
    sc[threadIdx.x] = v;
    __syncthreads();
#pragma unroll
    for (int off = 1; off < 256; off <<= 1) {
        int u = (threadIdx.x >= off) ? sc[threadIdx.x - off] : 0;
        __syncthreads();
        sc[threadIdx.x] += u;
        __syncthreads();
    }
    int excl = sc[threadIdx.x] - v;
    int node = j * 256 + threadIdx.x;
    if (node < NN) {
        deg[node] = v;
        offs[node] = s0 + excl;
        dis[node] = rsqrtf((float)(v + 1));  // +1 self-loop
    }
    cur[threadIdx.x] = excl;
    __syncthreads();
    for (int p = s0 + threadIdx.x; p < s1; p += 256) {
        int pk = csr_tmp[p];
        int dl = pk >> 17;
        int pos = s0 + atomicAdd(&cur[dl], 1);
        csr[pos] = pk & 0x1FFFF;   // plain src index
    }
}

// ---------- register-tiled GEMM (512 thr, 128 nodes/blk, 4x4/thread) ----------
template <int K, int FR, bool RELU>
__global__ __launch_bounds__(512) void k_gemm(const float* __restrict__ x,
                                              const float* __restrict__ W,
                                              const float* __restrict__ dis,
                                              u16* __restrict__ out) {
    __shared__ float xT[GT_KC * GT_STRIDE];   // 16,896 B
    __shared__ float Wc[GT_KC * 64];          //  8,192 B
    const int tid = threadIdx.x;
    const int r = tid >> 4;
    const int c = tid & 15;
    const int f4 = tid & 7;
    const int nrow = tid >> 3;
    const int nbase = blockIdx.x * GT_NODES;

    float acc[4][4];
#pragma unroll
    for (int i = 0; i < 4; ++i)
#pragma unroll
        for (int j = 0; j < 4; ++j) acc[i][j] = 0.f;

    for (int kc = 0; kc < K; kc += GT_KC) {
#pragma unroll
        for (int q = 0; q < 4; ++q) {
            int e = q * 512 + tid;
            int kk = e >> 6, j = e & 63;
            Wc[kk * 64 + j] = (j < FR) ? W[(size_t)(kc + kk) * FR + j] : 0.f;
        }
#pragma unroll
        for (int q = 0; q < 2; ++q) {
            int nl = q * 64 + nrow;
            int n = nbase + nl;
            float4 v = make_float4(0.f, 0.f, 0.f, 0.f);
            if (n < NN) v = *(const float4*)(x + (size_t)n * K + kc + f4 * 4);
            if (RELU) {
                v.x = fmaxf(v.x, 0.f); v.y = fmaxf(v.y, 0.f);
                v.z = fmaxf(v.z, 0.f); v.w = fmaxf(v.w, 0.f);
            }
            xT[(f4 * 4 + 0) * GT_STRIDE + nl] = v.x;
            xT[(f4 * 4 + 1) * GT_STRIDE + nl] = v.y;
            xT[(f4 * 4 + 2) * GT_STRIDE + nl] = v.z;
            xT[(f4 * 4 + 3) * GT_STRIDE + nl] = v.w;
        }
        __syncthreads();
#pragma unroll 8
        for (int kk = 0; kk < GT_KC; ++kk) {
            float4 a = *(const float4*)&xT[kk * GT_STRIDE + r * 4];
            float4 w = *(const float4*)&Wc[kk * 64 + c * 4];
            float xa[4] = {a.x, a.y, a.z, a.w};
            float wb[4] = {w.x, w.y, w.z, w.w};
#pragma unroll
            for (int i = 0; i < 4; ++i)
#pragma unroll
                for (int j = 0; j < 4; ++j)
                    acc[i][j] = fmaf(xa[i], wb[j], acc[i][j]);
        }
        __syncthreads();
    }
    if (c * 4 < FR) {
#pragma unroll
        for (int i = 0; i < 4; ++i) {
            int n = nbase + r * 4 + i;
            if (n < NN) {
                float dv = dis[n];
                uint2 o;
                o.x = pack2(dv * acc[i][0], dv * acc[i][1]);
                o.y = pack2(dv * acc[i][2], dv * acc[i][3]);
                *(uint2*)(out + (size_t)n * FR + c * 4) = o;
            }
        }
    }
}

// ---------- gather batch helper: B edges, SGPR row-base addressing ----------
// Indices delivered via v_readlane -> SGPR; row pointer g + s*F is wave-
// uniform so the backend forms it on the SALU pipe and each gather is
// global_load_ushort vdst, v_off(fc*2), s[base] -- ONE dest VGPR per
// outstanding load, so all B loads issue back-to-back with a single vmcnt
// drain (R12's per-lane flat addresses forced 2-VGPR addrs -> chunking).
// MASK=false batches skip the cndmask entirely. Masked lanes gather row 0
// (myidx init 0) -- hot line, L1-resident, then zeroed.
template <int F, int B, bool MASK>
__device__ __forceinline__ float gb(int myidx, int i, int lim,
                                    const u16* __restrict__ g, unsigned fc) {
    const u16* rp[B];
#pragma unroll
    for (int k = 0; k < B; ++k) {
        int s = __builtin_amdgcn_readlane(myidx, i + k);
        rp[k] = g + (size_t)(unsigned)s * (unsigned)F;   // uniform -> SGPR base
    }
    u16 hh[B];
#pragma unroll
    for (int k = 0; k < B; ++k) hh[k] = rp[k][fc];
    float t0 = 0.f, t1 = 0.f, t2 = 0.f, t3 = 0.f;
#pragma unroll
    for (int k = 0; k < B; ++k) {
        float v = bf2f(hh[k]);
        if (MASK) v = (i + k < lim) ? v : 0.f;
        if ((k & 3) == 0) t0 += v;
        else if ((k & 3) == 1) t1 += v;
        else if ((k & 3) == 2) t2 += v;
        else t3 += v;
    }
    return (t0 + t1) + (t2 + t3);
}

// ---------- gather aggregation (R13: staged-index + SGPR-base batches) -------
// out[n][f] = dis[n] * ( g[n][f] + sum_e g[src_e][f] ) + b[f]
// Stage up to 64 csr indices across the wave with ONE vector load; batch
// width picked by degree (uniform branch): deg<=16 -> one 16-batch,
// 17..32 -> one 32-batch, else full-16 loop + masked tail. >=98% of nodes
// take exactly ONE gather-latency exposure.
// Historical: int4 batching (R10), quad-rows (R9), s_load (R8) all slower.
template <int F, bool SOFTMAX>
__global__ __launch_bounds__(256) void k_gather(const int* __restrict__ offs,
                                                const int* __restrict__ deg,
                                                const int* __restrict__ csr,
                                                const float* __restrict__ dis,
                                                const u16* __restrict__ g,
                                                const float* __restrict__ b,
                                                float* __restrict__ out) {
    int n = blockIdx.x * 4 + (threadIdx.x >> 6);
    unsigned f = threadIdx.x & 63;
    if (n >= NN) return;
    unsigned fc = (f < (unsigned)F) ? f : 0u;
    int start = __builtin_amdgcn_readfirstlane(offs[n]);
    int len   = __builtin_amdgcn_readfirstlane(deg[n]);
    float dvn = dis[n];
    float bf  = b[fc];
    float acc = bf2f(g[(unsigned)n * F + fc]);  // self-loop (pre-scaled)

    // stage up to 64 csr indices across lanes (one vector load, masked)
    int myidx = 0;
    if ((int)f < len) myidx = csr[start + (int)f];
    int lim = (len < 64) ? len : 64;

    if (lim > 0) {
        if (lim >= 33) {
            int i = 0;
            for (; i + 16 <= lim; i += 16)
                acc += gb<F, 16, false>(myidx, i, lim, g, fc);
            if (i < lim)
                acc += gb<F, 16, true>(myidx, i, lim, g, fc);
        } else if (lim >= 17) {
            acc += gb<F, 32, true>(myidx, 0, lim, g, fc);
        } else if (lim == 16) {
            acc += gb<F, 16, false>(myidx, 0, lim, g, fc);
        } else {
            acc += gb<F, 16, true>(myidx, 0, lim, g, fc);
        }
    }

    // rare fallback: deg > 64 (essentially never for Poisson(16))
    if (len > 64) {
        int ii = 64;
        for (; ii + 2 <= len; ii += 2) {
            int s0 = __builtin_amdgcn_readfirstlane(csr[start + ii + 0]);
            int s1 = __builtin_amdgcn_readfirstlane(csr[start + ii + 1]);
            u16 h0 = g[(unsigned)s0 * F + fc];
            u16 h1 = g[(unsigned)s1 * F + fc];
            acc += bf2f(h0) + bf2f(h1);
        }
        if (ii < len) {
            int s0 = __builtin_amdgcn_readfirstlane(csr[start + ii]);
            acc += bf2f(g[(unsigned)s0 * F + fc]);
        }
    }

    float v = dvn * acc + bf;
    if (!SOFTMAX) {
        if (f < (unsigned)F) out[(size_t)n * F + f] = v;
    } else {
        float vv = (f < (unsigned)F) ? v : -INFINITY;
        float m = vv;
#pragma unroll
        for (int off = 32; off; off >>= 1) m = fmaxf(m, __shfl_xor(m, off));
        float ex = (f < (unsigned)F) ? __expf(vv - m) : 0.f;
        float sum = ex;
#pragma unroll
        for (int off = 32; off; off >>= 1) sum += __shfl_xor(sum, off);
        if (f < (unsigned)F) out[(size_t)n * F + f] = vv - m - logf(sum);
    }
}

extern "C" void kernel_launch(void* const* d_in, const int* in_sizes, int n_in,
                              void* d_out, int out_size, void* d_ws, size_t ws_size,
                              hipStream_t stream) {
    const float* x  = (const float*)d_in[0];
    const void*  ei = d_in[1];
    const float* W1 = (const float*)d_in[2];
    const float* b1 = (const float*)d_in[3];
    const float* W2 = (const float*)d_in[4];
    const float* b2 = (const float*)d_in[5];
    const float* W3 = (const float*)d_in[6];
    const float* b3 = (const float*)d_in[7];
    float* out = (float*)d_out;

    char* ws = (char*)d_ws;
    size_t off = 0;
    auto alloc = [&](size_t bytes) { void* p = ws + off; off += (bytes + 255) & ~255ULL; return p; };
    int*   cursor  = (int*)alloc(NB * 4);
    int*   deg     = (int*)alloc(NN * 4);
    float* dis     = (float*)alloc(NN * 4);
    int*   offs    = (int*)alloc(NN * 4);
    int*   csr_tmp = (int*)alloc((size_t)NB * CAP * 4);   // 8 MB padded
    int*   csr     = (int*)alloc((size_t)NB * CAP * 4);   // 8 MB padded
    u16*   gbuf    = (u16*)alloc((size_t)NN * 64 * 2);    // bf16 staging (12.8 MB)
    float* act     = (float*)alloc((size_t)NN * 64 * 4);  // fp32 inter-layer activations

    // CSR build: 2 kernels (padded-bucket counting sort, no global prefix)
    hipMemsetAsync(cursor, 0, NB * 4, stream);
    k_build<<<EB, 256, 0, stream>>>(ei, cursor, csr_tmp);
    k_sort<<<NB, 256, 0, stream>>>(cursor, csr_tmp, csr, deg, offs, dis);

    const int gemm_grid = (NN + GT_NODES - 1) / GT_NODES;   // 782
    const int gather_grid = (NN + 3) / 4;

    // layer 1: g1 = bf16(dis*(x@W1)); out1 = dis*(sum g1) + b1  (ReLU fused into next gemm)
    k_gemm<128, 64, false><<<gemm_grid, 512, 0, stream>>>(x, W1, dis, gbuf);
    k_gather<64, false><<<gather_grid, 256, 0, stream>>>(offs, deg, csr, dis, gbuf, b1, act);

    // layer 2
    k_gemm<64, 64, true><<<gemm_grid, 512, 0, stream>>>(act, W2, dis, gbuf);
    k_gather<64, false><<<gather_grid, 256, 0, stream>>>(offs, deg, csr, dis, gbuf, b2, act);

    // layer 3 + fused log_softmax (tight 40-wide staging rows)
    k_gemm<64, 40, true><<<gemm_grid, 512, 0, stream>>>(act, W3, dis, gbuf);
    k_gather<40, true><<<gather_grid, 256, 0, stream>>>(offs, deg, csr, dis, gbuf, b3, out);
}